// Round 8
// baseline (79.456 us; speedup 1.0000x reference)
//
#include <hip/hip_runtime.h>

#define LSEQ 8192
#define CH   256

typedef __attribute__((ext_vector_type(8)))  short short8;
typedef __attribute__((ext_vector_type(4)))  short short4v;
typedef __attribute__((ext_vector_type(16))) float f32x16;
typedef unsigned int u32;

__device__ inline short f2bf(float f) {
  union { float f; unsigned u; } v; v.f = f;
  unsigned r = v.u + 0x7fffu + ((v.u >> 16) & 1u);
  return (short)(r >> 16);
}
__device__ inline short8 cvt8(float4 a, float4 b) {
  short8 v;
  v[0] = f2bf(a.x); v[1] = f2bf(a.y); v[2] = f2bf(a.z); v[3] = f2bf(a.w);
  v[4] = f2bf(b.x); v[5] = f2bf(b.y); v[6] = f2bf(b.z); v[7] = f2bf(b.w);
  return v;
}
__device__ inline f32x16 mfma32(short8 a, short8 b, f32x16 c) {
  return __builtin_amdgcn_mfma_f32_32x32x16_bf16(a, b, c, 0, 0, 0);
}
// async global -> LDS, 16B per lane; dest = wave-uniform base (+ lane*16 by HW)
__device__ __forceinline__ void gload16(const void* g, void* l) {
  __builtin_amdgcn_global_load_lds(
      (const __attribute__((address_space(1))) u32*)g,
      (__attribute__((address_space(3))) u32*)l, 16, 0, 0);
}

// ---------------------------------------------------------------------------
// wprep: weights-only preprocessing + workspace zeroing (first launch).
//  b 0..15 : W2T[e][a] = sum_c Wq[c][e] Wk[c][a]  (64x64 tiles, bf16 out)
//  b 16/17 : Wkb/Wvb = bf16(W)
//  b 18    : g0[e] = sum_c bk[c] Wq[c][e]
//  b 19..22: zero M2 (256x512 fp32); b19 also zeros sx
// ---------------------------------------------------------------------------
__global__ __launch_bounds__(256) void wprep_kernel(
    const float* __restrict__ Wq, const float* __restrict__ Wk,
    const float* __restrict__ Wv, const float* __restrict__ bk,
    short* __restrict__ W2Tb, short* __restrict__ Wkb, short* __restrict__ Wvb,
    float* __restrict__ g0, float* __restrict__ M2, float* __restrict__ sx)
{
  __shared__ __align__(16) short aq[64 * 256];   // Wq^T tile [e][c]
  __shared__ __align__(16) short ak[64 * 256];   // Wk^T tile [a][c]
  const int b = blockIdx.x, tid = threadIdx.x;

  if (b < 16) {
    const int e0 = (b >> 2) * 64, a0 = (b & 3) * 64;
    // transpose-stage both operands (chunk swizzle ^(row&31))
#pragma unroll
    for (int i = 0; i < 16; ++i) {
      float4 vq = *(const float4*)(Wq + (size_t)tid * CH + e0 + i * 4);
      float4 vk = *(const float4*)(Wk + (size_t)tid * CH + a0 + i * 4);
      float q4[4] = {vq.x, vq.y, vq.z, vq.w};
      float k4[4] = {vk.x, vk.y, vk.z, vk.w};
#pragma unroll
      for (int j = 0; j < 4; ++j) {
        int rr = i * 4 + j;
        int off = rr * 256 + (((tid >> 3) ^ (rr & 31)) * 8) + (tid & 7);
        aq[off] = f2bf(q4[j]);
        ak[off] = f2bf(k4[j]);
      }
    }
    __syncthreads();

    const int wid = tid >> 6, lane = tid & 63, l31 = lane & 31, hi = lane >> 5;
    const int mt = wid >> 1, nt = wid & 1;
    f32x16 acc = {};
#pragma unroll
    for (int kd = 0; kd < 16; ++kd) {
      int ea = mt * 32 + l31;
      int aa = nt * 32 + l31;
      short8 af = *(const short8*)(&aq[ea * 256 + (((kd * 2 + hi) ^ (ea & 31)) * 8)]);
      short8 bf = *(const short8*)(&ak[aa * 256 + (((kd * 2 + hi) ^ (aa & 31)) * 8)]);
      acc = mfma32(af, bf, acc);
    }
    // D: col = a (B), row = e (A)
    int a = a0 + nt * 32 + l31;
#pragma unroll
    for (int r = 0; r < 16; ++r) {
      int e = e0 + mt * 32 + (r & 3) + 8 * (r >> 2) + 4 * hi;
      W2Tb[(size_t)e * CH + a] = f2bf(acc[r]);
    }
  } else if (b < 18) {
    const float* src = (b == 16) ? Wk : Wv;
    short* dst = (b == 16) ? Wkb : Wvb;
#pragma unroll
    for (int i = 0; i < 32; ++i) {
      int g = i * 256 + tid;
      const float4* s4 = (const float4*)(src + (size_t)g * 8);
      *(short8*)(dst + (size_t)g * 8) = cvt8(s4[0], s4[1]);
    }
  } else if (b == 18) {
    float acc = 0.f;
    for (int c = 0; c < 256; ++c)
      acc += bk[c] * Wq[(size_t)c * CH + tid];   // coalesced row reads
    g0[tid] = acc;
  } else {
    const int q = b - 19;                        // 4 blocks zero M2
    float4* p = (float4*)(M2 + (size_t)q * 32768);
    float4 z = {0.f, 0.f, 0.f, 0.f};
#pragma unroll
    for (int i = 0; i < 32; ++i) p[i * 256 + tid] = z;
    if (b == 19) sx[tid] = 0.f;
  }
}

// ---------------------------------------------------------------------------
// kvx: b<384: GEMM pass m = b>>7 over {K,V,G}: y = x@W^T + bias, transposed
//             bf16 output [out-dim][row]. W staged via gload16 (bf16).
//      b>=384: 64 blocks: xb = bf16(x) + sx col-sum atomics (128 rows each).
// ---------------------------------------------------------------------------
__global__ __launch_bounds__(256) void kvx_kernel(
    const float* __restrict__ x,
    const short* __restrict__ Wkb, const short* __restrict__ Wvb,
    const short* __restrict__ W2Tb,
    const float* __restrict__ bk, const float* __restrict__ bv,
    const float* __restrict__ g0,
    short* __restrict__ KTb, short* __restrict__ VTb, short* __restrict__ GTb,
    short* __restrict__ xb, float* __restrict__ sx)
{
  __shared__ __align__(16) char smem[128 * 256 * 2];   // 64KB
  const int b = blockIdx.x, tid = threadIdx.x;

  if (b < 384) {
    short* wt = (short*)smem;
    const int m = b >> 7, t = b & 127;
    const short* Wb = (m == 0) ? Wkb : ((m == 1) ? Wvb : W2Tb);
    const float* bp = (m == 0) ? bk : ((m == 1) ? bv : g0);
    short* dst = (m == 0) ? KTb : ((m == 1) ? VTb : GTb);
    const int rb = t >> 1, cb = t & 1;
    const int row0 = rb * 128, col0 = cb * 128;
    const int wid = tid >> 6, lane = tid & 63, l31 = lane & 31, hi = lane >> 5;

#pragma unroll
    for (int i = 0; i < 16; ++i) {
      int g = i * 256 + tid, rr = g >> 5, p = g & 31;
      gload16(Wb + (size_t)(col0 + rr) * CH + (p ^ (rr & 31)) * 8,
              &wt[(i * 256 + wid * 64) * 8]);
    }
    __syncthreads();

    const int wrow0 = row0 + wid * 32;
    f32x16 acc[4] = {};
#pragma unroll
    for (int kd = 0; kd < 16; ++kd) {
      const float4* xs = (const float4*)(x + (size_t)(wrow0 + l31) * CH + kd * 16 + hi * 8);
      short8 af = cvt8(xs[0], xs[1]);
#pragma unroll
      for (int nf = 0; nf < 4; ++nf) {
        int r = nf * 32 + l31;
        short8 bf = *(const short8*)(&wt[r * 256 + (((kd * 2 + hi) ^ (r & 31)) * 8)]);
        acc[nf] = mfma32(af, bf, acc[nf]);
      }
    }
    // transposed store: dst[col][row]
#pragma unroll
    for (int nf = 0; nf < 4; ++nf) {
      int col = col0 + nf * 32 + l31;
      float bias = bp[col];
#pragma unroll
      for (int g2 = 0; g2 < 4; ++g2) {
        short4v v;
#pragma unroll
        for (int r2 = 0; r2 < 4; ++r2) v[r2] = f2bf(acc[nf][g2 * 4 + r2] + bias);
        *(short4v*)(&dst[(size_t)col * LSEQ + wrow0 + g2 * 8 + hi * 4]) = v;
      }
    }
  } else {
    float (*red)[8] = (float(*)[8])smem;
    const int r0 = (b - 384) * 128;
    float part[8] = {};
#pragma unroll
    for (int i = 0; i < 16; ++i) {
      int g = i * 256 + tid;
      int row = r0 + (g >> 5), c8 = g & 31;     // c8 = tid&31, constant/thread
      const float4* src = (const float4*)(x + (size_t)row * CH + c8 * 8);
      float4 a = src[0], c = src[1];
      part[0] += a.x; part[1] += a.y; part[2] += a.z; part[3] += a.w;
      part[4] += c.x; part[5] += c.y; part[6] += c.z; part[7] += c.w;
      *(short8*)(xb + (size_t)row * CH + c8 * 8) = cvt8(a, c);
    }
#pragma unroll
    for (int j = 0; j < 8; ++j) red[tid][j] = part[j];
    __syncthreads();
    float s = 0.f;
#pragma unroll
    for (int k = 0; k < 8; ++k) s += red[(tid >> 3) + 32 * k][tid & 7];
    atomicAdd(&sx[tid], s);
  }
}

// ---------------------------------------------------------------------------
// gram2: M2[d][c'] (c'<256: MT = V^T K ; c'>=256: HT = V^T G), fp32 atomics.
// 256 blocks = 8 tiles (2 d x 4 c') x 32 L-splits.
// ---------------------------------------------------------------------------
__global__ __launch_bounds__(256) void gram_kernel(
    const short* __restrict__ VTb, const short* __restrict__ KTb,
    const short* __restrict__ GTb, float* __restrict__ M2)
{
  __shared__ __align__(16) short at[128 * 128];
  __shared__ __align__(16) short bt[128 * 128];

  const int tile = blockIdx.x & 7, split = blockIdx.x >> 3;
  const int d0 = (tile >> 2) * 128, ct = tile & 3;
  const short* Bsrc = (ct < 2) ? (KTb + (size_t)(ct * 128) * LSEQ)
                               : (GTb + (size_t)((ct - 2) * 128) * LSEQ);
  const int tid = threadIdx.x, wid = tid >> 6, lane = tid & 63;
  const int l31 = lane & 31, hi = lane >> 5;
  const int wr = wid >> 1, wc = wid & 1;

  f32x16 acc[2][2] = {};

#pragma unroll
  for (int jj = 0; jj < 2; ++jj) {
    const int j0 = split * 256 + jj * 128;
    __syncthreads();
#pragma unroll
    for (int i = 0; i < 8; ++i) {
      int g = i * 256 + tid, rr = g >> 4, p = g & 15;
      gload16(VTb + (size_t)(d0 + rr) * LSEQ + j0 + ((p ^ (rr & 15)) * 8),
              &at[(i * 256 + wid * 64) * 8]);
    }
#pragma unroll
    for (int i = 0; i < 8; ++i) {
      int g = i * 256 + tid, rr = g >> 4, p = g & 15;
      gload16(Bsrc + (size_t)rr * LSEQ + j0 + ((p ^ (rr & 15)) * 8),
              &bt[(i * 256 + wid * 64) * 8]);
    }
    __syncthreads();

#pragma unroll
    for (int kd = 0; kd < 8; ++kd) {
      int ra0 = wr * 64 + l31, ra1 = ra0 + 32;
      int rb0 = wc * 64 + l31, rb1 = rb0 + 32;
      int ck = kd * 2 + hi;
      short8 a0 = *(const short8*)(&at[ra0 * 128 + ((ck ^ (ra0 & 15)) * 8)]);
      short8 a1 = *(const short8*)(&at[ra1 * 128 + ((ck ^ (ra1 & 15)) * 8)]);
      short8 b0 = *(const short8*)(&bt[rb0 * 128 + ((ck ^ (rb0 & 15)) * 8)]);
      short8 b1 = *(const short8*)(&bt[rb1 * 128 + ((ck ^ (rb1 & 15)) * 8)]);
      acc[0][0] = mfma32(a0, b0, acc[0][0]);
      acc[0][1] = mfma32(a0, b1, acc[0][1]);
      acc[1][0] = mfma32(a1, b0, acc[1][0]);
      acc[1][1] = mfma32(a1, b1, acc[1][1]);
    }
  }

#pragma unroll
  for (int mt = 0; mt < 2; ++mt)
#pragma unroll
    for (int nt = 0; nt < 2; ++nt) {
      int ccol = ct * 128 + wc * 64 + nt * 32 + l31;
#pragma unroll
      for (int r = 0; r < 16; ++r) {
        int drow = d0 + wr * 64 + mt * 32 + (r & 3) + 8 * (r >> 2) + 4 * hi;
        atomicAdd(&M2[(size_t)drow * 512 + ccol], acc[mt][nt][r]);
      }
    }
}

// ---------------------------------------------------------------------------
// final: out[i][d] = (cv[d] + ((xb.HT^T)[i][d] + r[d])/L) / (L^2 + sq.sk/L)
// HT = M2[:,256:512] (fp32->bf16 LDS stage); scalars computed in-block:
//   sq[c] = Wq[c].sx + L bq[c]; sk analogous; cv[d] = Wv[d].sx + L bv[d];
//   r[d] = M2[d,0:256].bq.
// ---------------------------------------------------------------------------
__global__ __launch_bounds__(256) void final_kernel(
    const short* __restrict__ xb, const float* __restrict__ M2,
    const float* __restrict__ Wq, const float* __restrict__ Wk,
    const float* __restrict__ Wv, const float* __restrict__ bq,
    const float* __restrict__ bk, const float* __restrict__ bv,
    const float* __restrict__ sx, float* __restrict__ out)
{
  __shared__ __align__(16) short wt[128 * 256];   // 64KB HT slice
  __shared__ float sxl[256], bql[256], redzs[256], cvl[128], rl[128];

  const int tid = threadIdx.x;
  const int rb = blockIdx.x >> 1, cb = blockIdx.x & 1;
  const int row0 = rb * 128, col0 = cb * 128;

  sxl[tid] = sx[tid];
  bql[tid] = bq[tid];
  __syncthreads();

  // stage HT[d][e] for d in [col0, col0+128)
#pragma unroll
  for (int i = 0; i < 16; ++i) {
    int g = i * 256 + tid, rr = g >> 5, p = g & 31;
    const float4* src = (const float4*)(M2 + (size_t)(col0 + rr) * 512 + 256 + ((p ^ (rr & 31)) * 8));
    *(short8*)(&wt[rr * 256 + p * 8]) = cvt8(src[0], src[1]);
  }

  // zs partial: c = tid
  {
    const float4* wq4 = (const float4*)(Wq + (size_t)tid * CH);
    const float4* wk4 = (const float4*)(Wk + (size_t)tid * CH);
    float s1 = 0.f, s2 = 0.f;
#pragma unroll 4
    for (int e = 0; e < 256; e += 4) {
      float4 a = wq4[e >> 2], b2 = wk4[e >> 2];
      s1 += a.x * sxl[e] + a.y * sxl[e + 1] + a.z * sxl[e + 2] + a.w * sxl[e + 3];
      s2 += b2.x * sxl[e] + b2.y * sxl[e + 1] + b2.z * sxl[e + 2] + b2.w * sxl[e + 3];
    }
    redzs[tid] = (s1 + 8192.0f * bql[tid]) * (s2 + 8192.0f * bk[tid]);
  }

  // cv (tid<128) / r (tid>=128) for the block's d-slice
  if (tid < 128) {
    int d = col0 + tid;
    const float4* wv4 = (const float4*)(Wv + (size_t)d * CH);
    float s = 0.f;
#pragma unroll 4
    for (int e = 0; e < 256; e += 4) {
      float4 a = wv4[e >> 2];
      s += a.x * sxl[e] + a.y * sxl[e + 1] + a.z * sxl[e + 2] + a.w * sxl[e + 3];
    }
    cvl[tid] = s + 8192.0f * bv[d];
  } else {
    int d = col0 + tid - 128;
    const float4* m4 = (const float4*)(M2 + (size_t)d * 512);
    float s = 0.f;
#pragma unroll 4
    for (int c = 0; c < 256; c += 4) {
      float4 a = m4[c >> 2];
      s += a.x * bql[c] + a.y * bql[c + 1] + a.z * bql[c + 2] + a.w * bql[c + 3];
    }
    rl[tid - 128] = s;
  }
  __syncthreads();

#pragma unroll
  for (int st = 128; st > 0; st >>= 1) {
    if (tid < st) redzs[tid] += redzs[tid + st];
    __syncthreads();
  }
  const float Zinv = 1.0f / (67108864.0f + redzs[0] * (1.0f / 8192.0f));

  const int wid = tid >> 6, lane = tid & 63, l31 = lane & 31, hi = lane >> 5;
  const int wrow0 = row0 + wid * 32;

  f32x16 acc[4] = {};
#pragma unroll
  for (int kd = 0; kd < 16; ++kd) {
    short8 af = *(const short8*)(xb + (size_t)(wrow0 + l31) * CH + kd * 16 + hi * 8);
#pragma unroll
    for (int nf = 0; nf < 4; ++nf) {
      int r = nf * 32 + l31;
      short8 bf = *(const short8*)(&wt[r * 256 + (((kd * 2 + hi) ^ (r & 31)) * 8)]);
      acc[nf] = mfma32(af, bf, acc[nf]);
    }
  }

#pragma unroll
  for (int nf = 0; nf < 4; ++nf) {
    int dl = nf * 32 + l31;
    int d = col0 + dl;
    float cvd = cvl[dl], rd = rl[dl];
#pragma unroll
    for (int r = 0; r < 16; ++r) {
      int row = wrow0 + (r & 3) + 8 * (r >> 2) + 4 * hi;
      out[(size_t)row * CH + d] = (cvd + (acc[nf][r] + rd) * (1.0f / 8192.0f)) * Zinv;
    }
  }
}

// ---------------------------------------------------------------------------
extern "C" void kernel_launch(void* const* d_in, const int* in_sizes, int n_in,
                              void* d_out, int out_size, void* d_ws, size_t ws_size,
                              hipStream_t stream) {
  const float* x  = (const float*)d_in[0];
  const float* Wq = (const float*)d_in[1];
  const float* bq = (const float*)d_in[2];
  const float* Wk = (const float*)d_in[3];
  const float* bk = (const float*)d_in[4];
  const float* Wv = (const float*)d_in[5];
  const float* bv = (const float*)d_in[6];
  float* out = (float*)d_out;

  // ws: KT(4MB) | VT(4MB) | GT(4MB) | xb(4MB) | Wkb|Wvb|W2Tb (128KB each)
  //   | M2(512KB fp32) | g0(1KB) | sx(1KB)
  char* ws = (char*)d_ws;
  short* KTb  = (short*)ws;
  short* VTb  = KTb + (size_t)CH * LSEQ;
  short* GTb  = VTb + (size_t)CH * LSEQ;
  short* xb   = GTb + (size_t)CH * LSEQ;
  short* Wkb  = xb  + (size_t)LSEQ * CH;
  short* Wvb  = Wkb + (size_t)CH * CH;
  short* W2Tb = Wvb + (size_t)CH * CH;
  float* M2   = (float*)(W2Tb + (size_t)CH * CH);
  float* g0   = M2 + (size_t)CH * 512;
  float* sx   = g0 + CH;

  wprep_kernel<<<23, 256, 0, stream>>>(Wq, Wk, Wv, bk, W2Tb, Wkb, Wvb,
                                       g0, M2, sx);
  kvx_kernel<<<448, 256, 0, stream>>>(x, Wkb, Wvb, W2Tb, bk, bv, g0,
                                      KTb, VTb, GTb, xb, sx);
  gram_kernel<<<256, 256, 0, stream>>>(VTb, KTb, GTb, M2);
  final_kernel<<<128, 256, 0, stream>>>(xb, M2, Wq, Wk, Wv, bq, bk, bv,
                                        sx, out);
}

// Round 9
// 46.503 us; speedup vs baseline: 1.7086x; 1.7086x over previous
//
#include <hip/hip_runtime.h>

#define LSEQ 8192
#define CH   256

typedef __attribute__((ext_vector_type(8)))  short short8;
typedef __attribute__((ext_vector_type(4)))  short short4v;
typedef __attribute__((ext_vector_type(16))) float f32x16;
typedef unsigned int u32;

__device__ inline short f2bf(float f) {
  union { float f; unsigned u; } v; v.f = f;
  unsigned r = v.u + 0x7fffu + ((v.u >> 16) & 1u);
  return (short)(r >> 16);
}
__device__ inline short8 cvt8(float4 a, float4 b) {
  short8 v;
  v[0] = f2bf(a.x); v[1] = f2bf(a.y); v[2] = f2bf(a.z); v[3] = f2bf(a.w);
  v[4] = f2bf(b.x); v[5] = f2bf(b.y); v[6] = f2bf(b.z); v[7] = f2bf(b.w);
  return v;
}
__device__ inline f32x16 mfma32(short8 a, short8 b, f32x16 c) {
  return __builtin_amdgcn_mfma_f32_32x32x16_bf16(a, b, c, 0, 0, 0);
}
// async global -> LDS, 16B per lane; dest = wave-uniform base (+ lane*16 by HW)
__device__ __forceinline__ void gload16(const void* g, void* l) {
  __builtin_amdgcn_global_load_lds(
      (const __attribute__((address_space(1))) u32*)g,
      (__attribute__((address_space(3))) u32*)l, 16, 0, 0);
}

// ---------------------------------------------------------------------------
// Kernel 1: QKV projection, 128x128 tiles, 32x32x16 bf16 MFMA.
//   m=0 -> Qb [row][c] bf16 row-major       + sq[c]  = col-sums (atomic fp32)
//   m=1 -> KTb[c][row] bf16 transposed      + sk[c]
//   m=2 -> VTb[d][row] bf16 transposed      + colsum[d]
// W tile [128 outcols][256] fp32 -> bf16 LDS, 16B-chunk XOR swizzle ^(row&31).
// (verified round 6: 46.8 us total, absmax 1.19e-7)
// ---------------------------------------------------------------------------
__global__ __launch_bounds__(256) void qkv_kernel(
    const float* __restrict__ x,
    const float* __restrict__ Wq, const float* __restrict__ bq,
    const float* __restrict__ Wk, const float* __restrict__ bk,
    const float* __restrict__ Wv, const float* __restrict__ bv,
    short* __restrict__ Qb, short* __restrict__ KTb, short* __restrict__ VTb,
    float* __restrict__ sums)
{
  const int m = blockIdx.y;
  const float* W  = (m == 0) ? Wq : ((m == 1) ? Wk : Wv);
  const float* bp = (m == 0) ? bq : ((m == 1) ? bk : bv);
  const int rb = blockIdx.x >> 1, cb = blockIdx.x & 1;
  const int row0 = rb * 128, col0 = cb * 128;

  __shared__ __align__(16) short wt[128 * 256];   // 64KB
  __shared__ float colred[4][128];

  const int tid = threadIdx.x;
#pragma unroll
  for (int i = 0; i < 16; ++i) {
    int g = i * 256 + tid;             // 16B bf16 chunk (8 elems / 32B fp32)
    int rr = g >> 5, p = g & 31;
    const float4* src = (const float4*)(W + (col0 + rr) * CH + ((p ^ (rr & 31)) * 8));
    short8 v = cvt8(src[0], src[1]);
    *(short8*)(&wt[rr * 256 + p * 8]) = v;
  }
  __syncthreads();

  const int wid = tid >> 6, lane = tid & 63, l31 = lane & 31, hi = lane >> 5;
  const int wrow0 = row0 + wid * 32;

  f32x16 acc[4] = {};
#pragma unroll
  for (int kd = 0; kd < 16; ++kd) {
    const float4* xs = (const float4*)(x + (size_t)(wrow0 + l31) * CH + kd * 16 + hi * 8);
    short8 af = cvt8(xs[0], xs[1]);
#pragma unroll
    for (int nf = 0; nf < 4; ++nf) {
      int r = nf * 32 + l31;
      short8 bf = *(const short8*)(&wt[r * 256 + (((kd * 2 + hi) ^ (r & 31)) * 8)]);
      acc[nf] = mfma32(af, bf, acc[nf]);   // D: row=x-row, col=W-row(outcol)
    }
  }

  // D layout: col = l31 (+32*nf), row = wrow0 + (r&3) + 8*(r>>2) + 4*hi
#pragma unroll
  for (int nf = 0; nf < 4; ++nf) {
    int col = col0 + nf * 32 + l31;
    float bias = bp[col];
    float cs = 0.f;
    if (m == 0) {
#pragma unroll
      for (int r = 0; r < 16; ++r) {
        float y = acc[nf][r] + bias;
        cs += y;
        int row = wrow0 + (r & 3) + 8 * (r >> 2) + 4 * hi;
        Qb[(size_t)row * CH + col] = f2bf(y);
      }
    } else {
      short* dst = (m == 1) ? KTb : VTb;
#pragma unroll
      for (int g = 0; g < 4; ++g) {
        short4v v;
#pragma unroll
        for (int r2 = 0; r2 < 4; ++r2) {
          float y = acc[nf][g * 4 + r2] + bias;
          cs += y;
          v[r2] = f2bf(y);
        }
        *(short4v*)(&dst[(size_t)col * LSEQ + wrow0 + g * 8 + hi * 4]) = v;
      }
    }
    cs += __shfl_xor(cs, 32);          // add other hi-half: 32-row sum
    if (hi == 0) colred[wid][nf * 32 + l31] = cs;
  }
  __syncthreads();
  if (tid < 128) {
    float s = colred[0][tid] + colred[1][tid] + colred[2][tid] + colred[3][tid];
    atomicAdd(&sums[m * CH + col0 + tid], s);
  }
}

// ---------------------------------------------------------------------------
// Kernel 2: MT[d][c] = sum_j V[j][d] K[j][c]  (= V^T K), fp32 atomic accum.
// Grid 128 = 4 output tiles (128x128) x 32 L-splits (256 j each).
// Epilogue atomic order XOR-spread by split to decorrelate same-address
// bursts across the 32 contending blocks (values identical; bijective r2).
// ---------------------------------------------------------------------------
__global__ __launch_bounds__(256) void gram_kernel(
    const short* __restrict__ VTb, const short* __restrict__ KTb,
    float* __restrict__ MT)
{
  __shared__ __align__(16) short at[128 * 128];   // 32KB VT tile [d][j]
  __shared__ __align__(16) short bt[128 * 128];   // 32KB KT tile [c][j]

  const int tile = blockIdx.x & 3, split = blockIdx.x >> 2;
  const int d0 = (tile >> 1) * 128, c0 = (tile & 1) * 128;
  const int tid = threadIdx.x, wid = tid >> 6, lane = tid & 63;
  const int l31 = lane & 31, hi = lane >> 5;
  const int wr = wid >> 1, wc = wid & 1;

  f32x16 acc[2][2] = {};

#pragma unroll
  for (int jj = 0; jj < 2; ++jj) {
    const int j0 = split * 256 + jj * 128;
    __syncthreads();                   // prior-stage readers done
#pragma unroll
    for (int i = 0; i < 8; ++i) {
      int g = i * 256 + tid, rr = g >> 4, p = g & 15;
      gload16(VTb + (size_t)(d0 + rr) * LSEQ + j0 + ((p ^ (rr & 15)) * 8),
              &at[(i * 256 + wid * 64) * 8]);
    }
#pragma unroll
    for (int i = 0; i < 8; ++i) {
      int g = i * 256 + tid, rr = g >> 4, p = g & 15;
      gload16(KTb + (size_t)(c0 + rr) * LSEQ + j0 + ((p ^ (rr & 15)) * 8),
              &bt[(i * 256 + wid * 64) * 8]);
    }
    __syncthreads();                   // drains vmcnt + barrier

#pragma unroll
    for (int kd = 0; kd < 8; ++kd) {
      int ra0 = wr * 64 + l31, ra1 = ra0 + 32;
      int rb0 = wc * 64 + l31, rb1 = rb0 + 32;
      int ck = kd * 2 + hi;
      short8 a0 = *(const short8*)(&at[ra0 * 128 + ((ck ^ (ra0 & 15)) * 8)]);
      short8 a1 = *(const short8*)(&at[ra1 * 128 + ((ck ^ (ra1 & 15)) * 8)]);
      short8 b0 = *(const short8*)(&bt[rb0 * 128 + ((ck ^ (rb0 & 15)) * 8)]);
      short8 b1 = *(const short8*)(&bt[rb1 * 128 + ((ck ^ (rb1 & 15)) * 8)]);
      acc[0][0] = mfma32(a0, b0, acc[0][0]);
      acc[0][1] = mfma32(a0, b1, acc[0][1]);
      acc[1][0] = mfma32(a1, b0, acc[1][0]);
      acc[1][1] = mfma32(a1, b1, acc[1][1]);
    }
  }

  // D: row = d (A), col = c (B); accumulate across splits via fp32 atomics
#pragma unroll
  for (int mt = 0; mt < 2; ++mt)
#pragma unroll
    for (int nt = 0; nt < 2; ++nt) {
      int ccol = c0 + wc * 64 + nt * 32 + l31;
#pragma unroll
      for (int r = 0; r < 16; ++r) {
        int r2 = r ^ (split & 15);     // split-dependent issue order
        int drow = d0 + wr * 64 + mt * 32 + (r2 & 3) + 8 * (r2 >> 2) + 4 * hi;
        atomicAdd(&MT[drow * CH + ccol], acc[mt][nt][r2]);
      }
    }
}

// ---------------------------------------------------------------------------
// Kernel 3: out[i][d] = (colsum[d] + (Q MT^T)[i][d]/L) / (L^2 + sq.sk/L)
// Same tiling as qkv: "W" = MT fp32 [d][c] -> bf16 LDS; A = Q bf16 rows.
// (verified round 6)
// ---------------------------------------------------------------------------
__global__ __launch_bounds__(256) void final_kernel(
    const short* __restrict__ Qb, const float* __restrict__ MT,
    const float* __restrict__ sums, float* __restrict__ out)
{
  __shared__ __align__(16) short wt[128 * 256];   // 64KB
  __shared__ float zs[256];

  const int tid = threadIdx.x;
  zs[tid] = sums[tid] * sums[CH + tid];           // sq[c]*sk[c]
  __syncthreads();
#pragma unroll
  for (int st = 128; st > 0; st >>= 1) {
    if (tid < st) zs[tid] += zs[tid + st];
    __syncthreads();
  }
  const float Zinv = 1.0f / (67108864.0f + zs[0] * (1.0f / 8192.0f));

  const int rb = blockIdx.x >> 1, cb = blockIdx.x & 1;
  const int row0 = rb * 128, col0 = cb * 128;

#pragma unroll
  for (int i = 0; i < 16; ++i) {
    int g = i * 256 + tid;
    int rr = g >> 5, p = g & 31;
    const float4* src = (const float4*)(MT + (col0 + rr) * CH + ((p ^ (rr & 31)) * 8));
    short8 v = cvt8(src[0], src[1]);
    *(short8*)(&wt[rr * 256 + p * 8]) = v;
  }
  __syncthreads();

  const int wid = tid >> 6, lane = tid & 63, l31 = lane & 31, hi = lane >> 5;
  const int wrow0 = row0 + wid * 32;

  short8 qf[16];
#pragma unroll
  for (int kd = 0; kd < 16; ++kd)
    qf[kd] = *(const short8*)(Qb + (size_t)(wrow0 + l31) * CH + kd * 16 + hi * 8);

  f32x16 acc[4] = {};
#pragma unroll
  for (int kd = 0; kd < 16; ++kd)
#pragma unroll
    for (int nf = 0; nf < 4; ++nf) {
      int r = nf * 32 + l31;
      short8 bf = *(const short8*)(&wt[r * 256 + (((kd * 2 + hi) ^ (r & 31)) * 8)]);
      acc[nf] = mfma32(qf[kd], bf, acc[nf]);
    }

  const float* colsum = sums + 2 * CH;
#pragma unroll
  for (int nf = 0; nf < 4; ++nf) {
    int col = col0 + nf * 32 + l31;
    float cs = colsum[col];
#pragma unroll
    for (int r = 0; r < 16; ++r) {
      int row = wrow0 + (r & 3) + 8 * (r >> 2) + 4 * hi;
      out[(size_t)row * CH + col] = (cs + acc[nf][r] * (1.0f / 8192.0f)) * Zinv;
    }
  }
}

// ---------------------------------------------------------------------------
extern "C" void kernel_launch(void* const* d_in, const int* in_sizes, int n_in,
                              void* d_out, int out_size, void* d_ws, size_t ws_size,
                              hipStream_t stream) {
  const float* x  = (const float*)d_in[0];
  const float* Wq = (const float*)d_in[1];
  const float* bq = (const float*)d_in[2];
  const float* Wk = (const float*)d_in[3];
  const float* bk = (const float*)d_in[4];
  const float* Wv = (const float*)d_in[5];
  const float* bv = (const float*)d_in[6];
  float* out = (float*)d_out;

  // workspace: Q(4MB) | KT(4MB) | VT(4MB) | MT(256KB fp32) | sums(3KB)
  char* ws = (char*)d_ws;
  short* Qb  = (short*)ws;
  short* KTb = Qb  + (size_t)LSEQ * CH;
  short* VTb = KTb + (size_t)CH * LSEQ;
  float* MT   = (float*)(VTb + (size_t)CH * LSEQ);
  float* sums = MT + (size_t)CH * CH;          // [0]=sq, [1]=sk, [2]=colsum

  hipMemsetAsync(MT, 0, (size_t)CH * CH * sizeof(float) + 3 * CH * sizeof(float),
                 stream);

  qkv_kernel<<<dim3(128, 3), 256, 0, stream>>>(x, Wq, bq, Wk, bk, Wv, bv,
                                               Qb, KTb, VTb, sums);
  gram_kernel<<<128, 256, 0, stream>>>(VTb, KTb, MT);
  final_kernel<<<128, 256, 0, stream>>>(Qb, MT, sums, out);
}

// Round 10
// 39.308 us; speedup vs baseline: 2.0214x; 1.1831x over previous
//
#include <hip/hip_runtime.h>

#define LSEQ 8192
#define CH   256

typedef __attribute__((ext_vector_type(8)))  short short8;
typedef __attribute__((ext_vector_type(4)))  short short4v;
typedef __attribute__((ext_vector_type(16))) float f32x16;
typedef unsigned int u32;

__device__ inline short f2bf(float f) {
  union { float f; unsigned u; } v; v.f = f;
  unsigned r = v.u + 0x7fffu + ((v.u >> 16) & 1u);
  return (short)(r >> 16);
}
__device__ inline short8 cvt8(float4 a, float4 b) {
  short8 v;
  v[0] = f2bf(a.x); v[1] = f2bf(a.y); v[2] = f2bf(a.z); v[3] = f2bf(a.w);
  v[4] = f2bf(b.x); v[5] = f2bf(b.y); v[6] = f2bf(b.z); v[7] = f2bf(b.w);
  return v;
}
__device__ inline f32x16 mfma32(short8 a, short8 b, f32x16 c) {
  return __builtin_amdgcn_mfma_f32_32x32x16_bf16(a, b, c, 0, 0, 0);
}
// async global -> LDS, 16B per lane; dest = wave-uniform base (+ lane*16 by HW)
__device__ __forceinline__ void gload16(const void* g, void* l) {
  __builtin_amdgcn_global_load_lds(
      (const __attribute__((address_space(1))) u32*)g,
      (__attribute__((address_space(3))) u32*)l, 16, 0, 0);
}

// ---------------------------------------------------------------------------
// Kernel 1: QKV projection, 128x128 tiles, 32x32x16 bf16 MFMA.
//   m=0 -> Qb [row][c] bf16 row-major   (+ these blocks zero MT: plain stores)
//   m=1 -> KTb[c][row] bf16 transposed
//   m=2 -> VTb[d][row] bf16 transposed
// Column-sums: plain-stored partials sp[m][rb][col] (no atomics, no memset).
// W tile [128 outcols][256] fp32 -> bf16 LDS, 16B-chunk XOR swizzle ^(row&31).
// (GEMM core verified rounds 6/9)
// ---------------------------------------------------------------------------
__global__ __launch_bounds__(256) void qkv_kernel(
    const float* __restrict__ x,
    const float* __restrict__ Wq, const float* __restrict__ bq,
    const float* __restrict__ Wk, const float* __restrict__ bk,
    const float* __restrict__ Wv, const float* __restrict__ bv,
    short* __restrict__ Qb, short* __restrict__ KTb, short* __restrict__ VTb,
    float* __restrict__ sp, float* __restrict__ MT)
{
  const int m = blockIdx.y;
  const float* W  = (m == 0) ? Wq : ((m == 1) ? Wk : Wv);
  const float* bp = (m == 0) ? bq : ((m == 1) ? bk : bv);
  const int rb = blockIdx.x >> 1, cb = blockIdx.x & 1;
  const int row0 = rb * 128, col0 = cb * 128;

  __shared__ __align__(16) short wt[128 * 256];   // 64KB
  __shared__ float colred[4][128];

  const int tid = threadIdx.x;

  // m=0 blocks also zero MT (disjoint 512-float slices; read only by gram)
  if (m == 0 && tid < 128) {
    float4 z = {0.f, 0.f, 0.f, 0.f};
    ((float4*)(MT + (size_t)blockIdx.x * 512))[tid] = z;
  }

#pragma unroll
  for (int i = 0; i < 16; ++i) {
    int g = i * 256 + tid;             // 16B bf16 chunk (8 elems / 32B fp32)
    int rr = g >> 5, p = g & 31;
    const float4* src = (const float4*)(W + (col0 + rr) * CH + ((p ^ (rr & 31)) * 8));
    short8 v = cvt8(src[0], src[1]);
    *(short8*)(&wt[rr * 256 + p * 8]) = v;
  }
  __syncthreads();

  const int wid = tid >> 6, lane = tid & 63, l31 = lane & 31, hi = lane >> 5;
  const int wrow0 = row0 + wid * 32;

  f32x16 acc[4] = {};
#pragma unroll
  for (int kd = 0; kd < 16; ++kd) {
    const float4* xs = (const float4*)(x + (size_t)(wrow0 + l31) * CH + kd * 16 + hi * 8);
    short8 af = cvt8(xs[0], xs[1]);
#pragma unroll
    for (int nf = 0; nf < 4; ++nf) {
      int r = nf * 32 + l31;
      short8 bf = *(const short8*)(&wt[r * 256 + (((kd * 2 + hi) ^ (r & 31)) * 8)]);
      acc[nf] = mfma32(af, bf, acc[nf]);   // D: row=x-row, col=W-row(outcol)
    }
  }

  // D layout: col = l31 (+32*nf), row = wrow0 + (r&3) + 8*(r>>2) + 4*hi
#pragma unroll
  for (int nf = 0; nf < 4; ++nf) {
    int col = col0 + nf * 32 + l31;
    float bias = bp[col];
    float cs = 0.f;
    if (m == 0) {
#pragma unroll
      for (int r = 0; r < 16; ++r) {
        float y = acc[nf][r] + bias;
        cs += y;
        int row = wrow0 + (r & 3) + 8 * (r >> 2) + 4 * hi;
        Qb[(size_t)row * CH + col] = f2bf(y);
      }
    } else {
      short* dst = (m == 1) ? KTb : VTb;
#pragma unroll
      for (int g = 0; g < 4; ++g) {
        short4v v;
#pragma unroll
        for (int r2 = 0; r2 < 4; ++r2) {
          float y = acc[nf][g * 4 + r2] + bias;
          cs += y;
          v[r2] = f2bf(y);
        }
        *(short4v*)(&dst[(size_t)col * LSEQ + wrow0 + g * 8 + hi * 4]) = v;
      }
    }
    cs += __shfl_xor(cs, 32);          // add other hi-half: 32-row sum
    if (hi == 0) colred[wid][nf * 32 + l31] = cs;
  }
  __syncthreads();
  if (tid < 128) {
    float s = colred[0][tid] + colred[1][tid] + colred[2][tid] + colred[3][tid];
    sp[((size_t)m * 64 + rb) * 256 + col0 + tid] = s;   // plain partial store
  }
}

// ---------------------------------------------------------------------------
// Kernel 2: blocks 0..63: MT[d][c] += V^T K partials (fp32 atomics),
//   4 output tiles (128x128) x 16 L-splits (512 j each).
// block 64: scalar reductions of sp -> scal[0] = sum_c sq[c]*sk[c],
//   scal[1+d] = colsum[d].
// ---------------------------------------------------------------------------
__global__ __launch_bounds__(256) void gram_kernel(
    const short* __restrict__ VTb, const short* __restrict__ KTb,
    const float* __restrict__ sp, float* __restrict__ MT,
    float* __restrict__ scal)
{
  __shared__ __align__(16) short at[128 * 128];   // 32KB VT tile [d][j]
  __shared__ __align__(16) short bt[128 * 128];   // 32KB KT tile [c][j]

  const int tid = threadIdx.x;

  if (blockIdx.x == 64) {
    // scalar block: reduce partials (coalesced row-wise reads of sp)
    float s0 = 0.f, s1 = 0.f, s2 = 0.f;
    for (int rb = 0; rb < 64; ++rb) {
      s0 += sp[(size_t)(0 * 64 + rb) * 256 + tid];
      s1 += sp[(size_t)(1 * 64 + rb) * 256 + tid];
      s2 += sp[(size_t)(2 * 64 + rb) * 256 + tid];
    }
    scal[1 + tid] = s2;                // colsum
    float* red = (float*)at;
    red[tid] = s0 * s1;                // sq[c]*sk[c]
    __syncthreads();
#pragma unroll
    for (int st = 128; st > 0; st >>= 1) {
      if (tid < st) red[tid] += red[tid + st];
      __syncthreads();
    }
    if (tid == 0) scal[0] = red[0];
    return;
  }

  const int tile = blockIdx.x & 3, split = blockIdx.x >> 2;   // split 0..15
  const int d0 = (tile >> 1) * 128, c0 = (tile & 1) * 128;
  const int wid = tid >> 6, lane = tid & 63;
  const int l31 = lane & 31, hi = lane >> 5;
  const int wr = wid >> 1, wc = wid & 1;

  f32x16 acc[2][2] = {};

#pragma unroll
  for (int jj = 0; jj < 4; ++jj) {
    const int j0 = split * 512 + jj * 128;
    __syncthreads();                   // prior-stage readers done
#pragma unroll
    for (int i = 0; i < 8; ++i) {
      int g = i * 256 + tid, rr = g >> 4, p = g & 15;
      gload16(VTb + (size_t)(d0 + rr) * LSEQ + j0 + ((p ^ (rr & 15)) * 8),
              &at[(i * 256 + wid * 64) * 8]);
    }
#pragma unroll
    for (int i = 0; i < 8; ++i) {
      int g = i * 256 + tid, rr = g >> 4, p = g & 15;
      gload16(KTb + (size_t)(c0 + rr) * LSEQ + j0 + ((p ^ (rr & 15)) * 8),
              &bt[(i * 256 + wid * 64) * 8]);
    }
    __syncthreads();                   // drains vmcnt + barrier

#pragma unroll
    for (int kd = 0; kd < 8; ++kd) {
      int ra0 = wr * 64 + l31, ra1 = ra0 + 32;
      int rb0 = wc * 64 + l31, rb1 = rb0 + 32;
      int ck = kd * 2 + hi;
      short8 a0 = *(const short8*)(&at[ra0 * 128 + ((ck ^ (ra0 & 15)) * 8)]);
      short8 a1 = *(const short8*)(&at[ra1 * 128 + ((ck ^ (ra1 & 15)) * 8)]);
      short8 b0 = *(const short8*)(&bt[rb0 * 128 + ((ck ^ (rb0 & 15)) * 8)]);
      short8 b1 = *(const short8*)(&bt[rb1 * 128 + ((ck ^ (rb1 & 15)) * 8)]);
      acc[0][0] = mfma32(a0, b0, acc[0][0]);
      acc[0][1] = mfma32(a0, b1, acc[0][1]);
      acc[1][0] = mfma32(a1, b0, acc[1][0]);
      acc[1][1] = mfma32(a1, b1, acc[1][1]);
    }
  }

  // D: row = d (A), col = c (B); accumulate across splits via fp32 atomics
#pragma unroll
  for (int mt = 0; mt < 2; ++mt)
#pragma unroll
    for (int nt = 0; nt < 2; ++nt) {
      int ccol = c0 + wc * 64 + nt * 32 + l31;
#pragma unroll
      for (int r = 0; r < 16; ++r) {
        int r2 = r ^ (split & 15);     // split-dependent issue order
        int drow = d0 + wr * 64 + mt * 32 + (r2 & 3) + 8 * (r2 >> 2) + 4 * hi;
        atomicAdd(&MT[drow * CH + ccol], acc[mt][nt][r2]);
      }
    }
}

// ---------------------------------------------------------------------------
// Kernel 3: out[i][d] = (colsum[d] + (Q MT^T)[i][d]/L) / (L^2 + zs/L)
// zs/colsum precomputed in gram's scalar block (scal[0], scal[1+d]).
// Same tiling as qkv: "W" = MT fp32 [d][c] -> bf16 LDS; A = Q bf16 rows.
// ---------------------------------------------------------------------------
__global__ __launch_bounds__(256) void final_kernel(
    const short* __restrict__ Qb, const float* __restrict__ MT,
    const float* __restrict__ scal, float* __restrict__ out)
{
  __shared__ __align__(16) short wt[128 * 256];   // 64KB

  const int tid = threadIdx.x;
  const float Zinv = 1.0f / (67108864.0f + scal[0] * (1.0f / 8192.0f));

  const int rb = blockIdx.x >> 1, cb = blockIdx.x & 1;
  const int row0 = rb * 128, col0 = cb * 128;

#pragma unroll
  for (int i = 0; i < 16; ++i) {
    int g = i * 256 + tid;
    int rr = g >> 5, p = g & 31;
    const float4* src = (const float4*)(MT + (col0 + rr) * CH + ((p ^ (rr & 31)) * 8));
    short8 v = cvt8(src[0], src[1]);
    *(short8*)(&wt[rr * 256 + p * 8]) = v;
  }
  __syncthreads();

  const int wid = tid >> 6, lane = tid & 63, l31 = lane & 31, hi = lane >> 5;
  const int wrow0 = row0 + wid * 32;

  short8 qf[16];
#pragma unroll
  for (int kd = 0; kd < 16; ++kd)
    qf[kd] = *(const short8*)(Qb + (size_t)(wrow0 + l31) * CH + kd * 16 + hi * 8);

  f32x16 acc[4] = {};
#pragma unroll
  for (int kd = 0; kd < 16; ++kd)
#pragma unroll
    for (int nf = 0; nf < 4; ++nf) {
      int r = nf * 32 + l31;
      short8 bf = *(const short8*)(&wt[r * 256 + (((kd * 2 + hi) ^ (r & 31)) * 8)]);
      acc[nf] = mfma32(qf[kd], bf, acc[nf]);
    }

#pragma unroll
  for (int nf = 0; nf < 4; ++nf) {
    int col = col0 + nf * 32 + l31;
    float cs = scal[1 + col];
#pragma unroll
    for (int r = 0; r < 16; ++r) {
      int row = wrow0 + (r & 3) + 8 * (r >> 2) + 4 * hi;
      out[(size_t)row * CH + col] = (cs + acc[nf][r] * (1.0f / 8192.0f)) * Zinv;
    }
  }
}

// ---------------------------------------------------------------------------
extern "C" void kernel_launch(void* const* d_in, const int* in_sizes, int n_in,
                              void* d_out, int out_size, void* d_ws, size_t ws_size,
                              hipStream_t stream) {
  const float* x  = (const float*)d_in[0];
  const float* Wq = (const float*)d_in[1];
  const float* bq = (const float*)d_in[2];
  const float* Wk = (const float*)d_in[3];
  const float* bk = (const float*)d_in[4];
  const float* Wv = (const float*)d_in[5];
  const float* bv = (const float*)d_in[6];
  float* out = (float*)d_out;

  // workspace: Q(4MB) | KT(4MB) | VT(4MB) | MT(256KB) | sp(192KB) | scal(1KB+)
  char* ws = (char*)d_ws;
  short* Qb  = (short*)ws;
  short* KTb = Qb  + (size_t)LSEQ * CH;
  short* VTb = KTb + (size_t)CH * LSEQ;
  float* MT   = (float*)(VTb + (size_t)CH * LSEQ);
  float* sp   = MT + (size_t)CH * CH;          // [3][64][256] partial col-sums
  float* scal = sp + (size_t)3 * 64 * 256;     // [0]=zs, [1..256]=colsum

  qkv_kernel<<<dim3(128, 3), 256, 0, stream>>>(x, Wq, bq, Wk, bk, Wv, bv,
                                               Qb, KTb, VTb, sp, MT);
  gram_kernel<<<65, 256, 0, stream>>>(VTb, KTb, sp, MT, scal);
  final_kernel<<<128, 256, 0, stream>>>(Qb, MT, scal, out);
}

// Round 11
// 39.151 us; speedup vs baseline: 2.0295x; 1.0040x over previous
//
#include <hip/hip_runtime.h>

#define LSEQ 8192
#define CH   256

typedef __attribute__((ext_vector_type(8)))  short short8;
typedef __attribute__((ext_vector_type(4)))  short short4v;
typedef __attribute__((ext_vector_type(16))) float f32x16;
typedef unsigned int u32;

// Single bf16 convert: v_cvt_pk_bf16_f32 (RNE, 1 inst; low half used).
__device__ __forceinline__ short f2bf(float f) {
  u32 r;
  asm("v_cvt_pk_bf16_f32 %0, %1, %1" : "=v"(r) : "v"(f));
  return (short)r;
}
__device__ __forceinline__ u32 pk2bf(float a, float b) {
  u32 r;
  asm("v_cvt_pk_bf16_f32 %0, %1, %2" : "=v"(r) : "v"(a), "v"(b));
  return r;
}
__device__ __forceinline__ short8 cvt8(float4 a, float4 b) {
  union { u32 u[4]; short8 s; } v;
  v.u[0] = pk2bf(a.x, a.y); v.u[1] = pk2bf(a.z, a.w);
  v.u[2] = pk2bf(b.x, b.y); v.u[3] = pk2bf(b.z, b.w);
  return v.s;
}
__device__ __forceinline__ short4v pk4bf(float a, float b, float c, float d) {
  union { u32 u[2]; short4v s; } v;
  v.u[0] = pk2bf(a, b); v.u[1] = pk2bf(c, d);
  return v.s;
}
__device__ inline f32x16 mfma32(short8 a, short8 b, f32x16 c) {
  return __builtin_amdgcn_mfma_f32_32x32x16_bf16(a, b, c, 0, 0, 0);
}
// async global -> LDS, 16B per lane; dest = wave-uniform base (+ lane*16 by HW)
__device__ __forceinline__ void gload16(const void* g, void* l) {
  __builtin_amdgcn_global_load_lds(
      (const __attribute__((address_space(1))) u32*)g,
      (__attribute__((address_space(3))) u32*)l, 16, 0, 0);
}

// ---------------------------------------------------------------------------
// Kernel 1: QKV projection, 128x128 tiles, 32x32x16 bf16 MFMA.
//   m=0 -> Qb [row][c] bf16 row-major   (+ these blocks zero MT: plain stores)
//   m=1 -> KTb[c][row] bf16 transposed
//   m=2 -> VTb[d][row] bf16 transposed
// Column-sums: plain-stored partials sp[m][rb][col] (no atomics, no memset).
// W tile [128 outcols][256] fp32 -> bf16 LDS, 16B-chunk XOR swizzle ^(row&31).
// (structure verified R10 = 39.3us; this round: cvt_pk conversions only)
// ---------------------------------------------------------------------------
__global__ __launch_bounds__(256) void qkv_kernel(
    const float* __restrict__ x,
    const float* __restrict__ Wq, const float* __restrict__ bq,
    const float* __restrict__ Wk, const float* __restrict__ bk,
    const float* __restrict__ Wv, const float* __restrict__ bv,
    short* __restrict__ Qb, short* __restrict__ KTb, short* __restrict__ VTb,
    float* __restrict__ sp, float* __restrict__ MT)
{
  const int m = blockIdx.y;
  const float* W  = (m == 0) ? Wq : ((m == 1) ? Wk : Wv);
  const float* bp = (m == 0) ? bq : ((m == 1) ? bk : bv);
  const int rb = blockIdx.x >> 1, cb = blockIdx.x & 1;
  const int row0 = rb * 128, col0 = cb * 128;

  __shared__ __align__(16) short wt[128 * 256];   // 64KB
  __shared__ float colred[4][128];

  const int tid = threadIdx.x;

  // m=0 blocks also zero MT (disjoint 512-float slices; read only by gram)
  if (m == 0 && tid < 128) {
    float4 z = {0.f, 0.f, 0.f, 0.f};
    ((float4*)(MT + (size_t)blockIdx.x * 512))[tid] = z;
  }

#pragma unroll
  for (int i = 0; i < 16; ++i) {
    int g = i * 256 + tid;             // 16B bf16 chunk (8 elems / 32B fp32)
    int rr = g >> 5, p = g & 31;
    const float4* src = (const float4*)(W + (col0 + rr) * CH + ((p ^ (rr & 31)) * 8));
    short8 v = cvt8(src[0], src[1]);
    *(short8*)(&wt[rr * 256 + p * 8]) = v;
  }
  __syncthreads();

  const int wid = tid >> 6, lane = tid & 63, l31 = lane & 31, hi = lane >> 5;
  const int wrow0 = row0 + wid * 32;

  f32x16 acc[4] = {};
#pragma unroll
  for (int kd = 0; kd < 16; ++kd) {
    const float4* xs = (const float4*)(x + (size_t)(wrow0 + l31) * CH + kd * 16 + hi * 8);
    short8 af = cvt8(xs[0], xs[1]);
#pragma unroll
    for (int nf = 0; nf < 4; ++nf) {
      int r = nf * 32 + l31;
      short8 bf = *(const short8*)(&wt[r * 256 + (((kd * 2 + hi) ^ (r & 31)) * 8)]);
      acc[nf] = mfma32(af, bf, acc[nf]);   // D: row=x-row, col=W-row(outcol)
    }
  }

  // D layout: col = l31 (+32*nf), row = wrow0 + (r&3) + 8*(r>>2) + 4*hi
#pragma unroll
  for (int nf = 0; nf < 4; ++nf) {
    int col = col0 + nf * 32 + l31;
    float bias = bp[col];
    float cs = 0.f;
    if (m == 0) {
#pragma unroll
      for (int r = 0; r < 16; ++r) {
        float y = acc[nf][r] + bias;
        cs += y;
        int row = wrow0 + (r & 3) + 8 * (r >> 2) + 4 * hi;
        Qb[(size_t)row * CH + col] = f2bf(y);
      }
    } else {
      short* dst = (m == 1) ? KTb : VTb;
#pragma unroll
      for (int g = 0; g < 4; ++g) {
        float y0 = acc[nf][g * 4 + 0] + bias;
        float y1 = acc[nf][g * 4 + 1] + bias;
        float y2 = acc[nf][g * 4 + 2] + bias;
        float y3 = acc[nf][g * 4 + 3] + bias;
        cs += (y0 + y1) + (y2 + y3);
        *(short4v*)(&dst[(size_t)col * LSEQ + wrow0 + g * 8 + hi * 4]) =
            pk4bf(y0, y1, y2, y3);
      }
    }
    cs += __shfl_xor(cs, 32);          // add other hi-half: 32-row sum
    if (hi == 0) colred[wid][nf * 32 + l31] = cs;
  }
  __syncthreads();
  if (tid < 128) {
    float s = colred[0][tid] + colred[1][tid] + colred[2][tid] + colred[3][tid];
    sp[((size_t)m * 64 + rb) * 256 + col0 + tid] = s;   // plain partial store
  }
}

// ---------------------------------------------------------------------------
// Kernel 2: blocks 0..63: MT[d][c] += V^T K partials (fp32 atomics),
//   4 output tiles (128x128) x 16 L-splits (512 j each).
// block 64: scalar reductions of sp -> scal[0] = sum_c sq[c]*sk[c],
//   scal[1+d] = colsum[d].
// ---------------------------------------------------------------------------
__global__ __launch_bounds__(256) void gram_kernel(
    const short* __restrict__ VTb, const short* __restrict__ KTb,
    const float* __restrict__ sp, float* __restrict__ MT,
    float* __restrict__ scal)
{
  __shared__ __align__(16) short at[128 * 128];   // 32KB VT tile [d][j]
  __shared__ __align__(16) short bt[128 * 128];   // 32KB KT tile [c][j]

  const int tid = threadIdx.x;

  if (blockIdx.x == 64) {
    // scalar block: reduce partials (coalesced row-wise reads of sp)
    float s0 = 0.f, s1 = 0.f, s2 = 0.f;
    for (int rb = 0; rb < 64; ++rb) {
      s0 += sp[(size_t)(0 * 64 + rb) * 256 + tid];
      s1 += sp[(size_t)(1 * 64 + rb) * 256 + tid];
      s2 += sp[(size_t)(2 * 64 + rb) * 256 + tid];
    }
    scal[1 + tid] = s2;                // colsum
    float* red = (float*)at;
    red[tid] = s0 * s1;                // sq[c]*sk[c]
    __syncthreads();
#pragma unroll
    for (int st = 128; st > 0; st >>= 1) {
      if (tid < st) red[tid] += red[tid + st];
      __syncthreads();
    }
    if (tid == 0) scal[0] = red[0];
    return;
  }

  const int tile = blockIdx.x & 3, split = blockIdx.x >> 2;   // split 0..15
  const int d0 = (tile >> 1) * 128, c0 = (tile & 1) * 128;
  const int wid = tid >> 6, lane = tid & 63;
  const int l31 = lane & 31, hi = lane >> 5;
  const int wr = wid >> 1, wc = wid & 1;

  f32x16 acc[2][2] = {};

#pragma unroll
  for (int jj = 0; jj < 4; ++jj) {
    const int j0 = split * 512 + jj * 128;
    __syncthreads();                   // prior-stage readers done
#pragma unroll
    for (int i = 0; i < 8; ++i) {
      int g = i * 256 + tid, rr = g >> 4, p = g & 15;
      gload16(VTb + (size_t)(d0 + rr) * LSEQ + j0 + ((p ^ (rr & 15)) * 8),
              &at[(i * 256 + wid * 64) * 8]);
    }
#pragma unroll
    for (int i = 0; i < 8; ++i) {
      int g = i * 256 + tid, rr = g >> 4, p = g & 15;
      gload16(KTb + (size_t)(c0 + rr) * LSEQ + j0 + ((p ^ (rr & 15)) * 8),
              &bt[(i * 256 + wid * 64) * 8]);
    }
    __syncthreads();                   // drains vmcnt + barrier

#pragma unroll
    for (int kd = 0; kd < 8; ++kd) {
      int ra0 = wr * 64 + l31, ra1 = ra0 + 32;
      int rb0 = wc * 64 + l31, rb1 = rb0 + 32;
      int ck = kd * 2 + hi;
      short8 a0 = *(const short8*)(&at[ra0 * 128 + ((ck ^ (ra0 & 15)) * 8)]);
      short8 a1 = *(const short8*)(&at[ra1 * 128 + ((ck ^ (ra1 & 15)) * 8)]);
      short8 b0 = *(const short8*)(&bt[rb0 * 128 + ((ck ^ (rb0 & 15)) * 8)]);
      short8 b1 = *(const short8*)(&bt[rb1 * 128 + ((ck ^ (rb1 & 15)) * 8)]);
      acc[0][0] = mfma32(a0, b0, acc[0][0]);
      acc[0][1] = mfma32(a0, b1, acc[0][1]);
      acc[1][0] = mfma32(a1, b0, acc[1][0]);
      acc[1][1] = mfma32(a1, b1, acc[1][1]);
    }
  }

  // D: row = d (A), col = c (B); accumulate across splits via fp32 atomics
#pragma unroll
  for (int mt = 0; mt < 2; ++mt)
#pragma unroll
    for (int nt = 0; nt < 2; ++nt) {
      int ccol = c0 + wc * 64 + nt * 32 + l31;
#pragma unroll
      for (int r = 0; r < 16; ++r) {
        int r2 = r ^ (split & 15);     // split-dependent issue order
        int drow = d0 + wr * 64 + mt * 32 + (r2 & 3) + 8 * (r2 >> 2) + 4 * hi;
        atomicAdd(&MT[drow * CH + ccol], acc[mt][nt][r2]);
      }
    }
}

// ---------------------------------------------------------------------------
// Kernel 3: out[i][d] = (colsum[d] + (Q MT^T)[i][d]/L) / (L^2 + zs/L)
// zs/colsum precomputed in gram's scalar block (scal[0], scal[1+d]).
// Same tiling as qkv: "W" = MT fp32 [d][c] -> bf16 LDS; A = Q bf16 rows.
// ---------------------------------------------------------------------------
__global__ __launch_bounds__(256) void final_kernel(
    const short* __restrict__ Qb, const float* __restrict__ MT,
    const float* __restrict__ scal, float* __restrict__ out)
{
  __shared__ __align__(16) short wt[128 * 256];   // 64KB

  const int tid = threadIdx.x;
  const float Zinv = 1.0f / (67108864.0f + scal[0] * (1.0f / 8192.0f));

  const int rb = blockIdx.x >> 1, cb = blockIdx.x & 1;
  const int row0 = rb * 128, col0 = cb * 128;

#pragma unroll
  for (int i = 0; i < 16; ++i) {
    int g = i * 256 + tid;
    int rr = g >> 5, p = g & 31;
    const float4* src = (const float4*)(MT + (col0 + rr) * CH + ((p ^ (rr & 31)) * 8));
    short8 v = cvt8(src[0], src[1]);
    *(short8*)(&wt[rr * 256 + p * 8]) = v;
  }
  __syncthreads();

  const int wid = tid >> 6, lane = tid & 63, l31 = lane & 31, hi = lane >> 5;
  const int wrow0 = row0 + wid * 32;

  short8 qf[16];
#pragma unroll
  for (int kd = 0; kd < 16; ++kd)
    qf[kd] = *(const short8*)(Qb + (size_t)(wrow0 + l31) * CH + kd * 16 + hi * 8);

  f32x16 acc[4] = {};
#pragma unroll
  for (int kd = 0; kd < 16; ++kd)
#pragma unroll
    for (int nf = 0; nf < 4; ++nf) {
      int r = nf * 32 + l31;
      short8 bf = *(const short8*)(&wt[r * 256 + (((kd * 2 + hi) ^ (r & 31)) * 8)]);
      acc[nf] = mfma32(qf[kd], bf, acc[nf]);
    }

#pragma unroll
  for (int nf = 0; nf < 4; ++nf) {
    int col = col0 + nf * 32 + l31;
    float cs = scal[1 + col];
#pragma unroll
    for (int r = 0; r < 16; ++r) {
      int row = wrow0 + (r & 3) + 8 * (r >> 2) + 4 * hi;
      out[(size_t)row * CH + col] = (cs + acc[nf][r] * (1.0f / 8192.0f)) * Zinv;
    }
  }
}

// ---------------------------------------------------------------------------
extern "C" void kernel_launch(void* const* d_in, const int* in_sizes, int n_in,
                              void* d_out, int out_size, void* d_ws, size_t ws_size,
                              hipStream_t stream) {
  const float* x  = (const float*)d_in[0];
  const float* Wq = (const float*)d_in[1];
  const float* bq = (const float*)d_in[2];
  const float* Wk = (const float*)d_in[3];
  const float* bk = (const float*)d_in[4];
  const float* Wv = (const float*)d_in[5];
  const float* bv = (const float*)d_in[6];
  float* out = (float*)d_out;

  // workspace: Q(4MB) | KT(4MB) | VT(4MB) | MT(256KB) | sp(192KB) | scal(1KB+)
  char* ws = (char*)d_ws;
  short* Qb  = (short*)ws;
  short* KTb = Qb  + (size_t)LSEQ * CH;
  short* VTb = KTb + (size_t)CH * LSEQ;
  float* MT   = (float*)(VTb + (size_t)CH * LSEQ);
  float* sp   = MT + (size_t)CH * CH;          // [3][64][256] partial col-sums
  float* scal = sp + (size_t)3 * 64 * 256;     // [0]=zs, [1..256]=colsum

  qkv_kernel<<<dim3(128, 3), 256, 0, stream>>>(x, Wq, bq, Wk, bk, Wv, bv,
                                               Qb, KTb, VTb, sp, MT);
  gram_kernel<<<65, 256, 0, stream>>>(VTb, KTb, sp, MT, scal);
  final_kernel<<<128, 256, 0, stream>>>(Qb, MT, scal, out);
}